// Round 2
// baseline (297.715 us; speedup 1.0000x reference)
//
#include <hip/hip_runtime.h>
#include <math.h>

// Problem constants
#define B_   64
#define L_   577
#define D_   512
#define E_   1024
#define H_   512
#define K_   288            // selected tokens per batch
#define N_   (B_ * K_)      // 18432 total rows
#define KBIG 1024           // concatenated K for fused GEMM2
#define MTILES (N_ / 128)   // 144

typedef __attribute__((ext_vector_type(8))) __bf16 bf16x8;
typedef __attribute__((ext_vector_type(4))) float f32x4;
typedef __attribute__((ext_vector_type(4))) unsigned short ushort4v;
typedef __attribute__((ext_vector_type(8))) unsigned short ushort8v;

// ---------------- workspace layout (bytes) ----------------
#define OFF_WBIG    0                    // 1024*1024 bf16 = 2,097,152
#define OFF_W0B     2097152              // 512*512 bf16   =   524,288
#define OFF_BIASBIG 2621440              // 1024 f32
#define OFF_SCSH    2625536              // 1024 f32 (sc=rsig*gamma, sh=beta-mu*sc)
#define OFF_IDX     2629632              // 18432 i32 = 73,728
#define OFF_PSUM    2703360              // 512 f32 sum + 512 f32 sumsq (atomic)
#define OFF_OUTENC  3293184              // 64*1024 u32 = 262,144
#define OFF_ABIG    3555328              // N*1024 bf16 = 37,748,736

static __device__ __forceinline__ unsigned short f2bf(float f) {
  unsigned int u = __builtin_bit_cast(unsigned int, f);
  u = (u + 0x7fffu + ((u >> 16) & 1u)) >> 16;
  return (unsigned short)u;
}
static __device__ __forceinline__ float bf2f(unsigned short s) {
  unsigned int u = ((unsigned int)s) << 16;
  return __builtin_bit_cast(float, u);
}

// monotone fp32 <-> uint encoding for atomicMax on floats
static __device__ __forceinline__ unsigned int encf(float f) {
  unsigned int u = __builtin_bit_cast(unsigned int, f);
  return (u & 0x80000000u) ? ~u : (u | 0x80000000u);
}
static __device__ __forceinline__ float decf(unsigned int e) {
  unsigned int u = (e & 0x80000000u) ? (e ^ 0x80000000u) : ~e;
  return __builtin_bit_cast(float, u);
}

#define GLOAD_LDS16(g, l)                                          \
  __builtin_amdgcn_global_load_lds(                                \
      (const __attribute__((address_space(1))) void*)(g),          \
      (__attribute__((address_space(3))) void*)(l), 16, 0, 0)

// ---------------- kernel 1: pack Wbig(bf16)=[fc_w|mlp_w1], biasbig=fc_b+b1,
//                  W0(bf16), zero outenc + psum/psq, AND top-k (fused)
__global__ __launch_bounds__(256) void prep_topk_kernel(
    const float* __restrict__ fc_w, const float* __restrict__ fc_b,
    const float* __restrict__ w0,   const float* __restrict__ w1,
    const float* __restrict__ b1,   const float* __restrict__ atten,
    unsigned short* __restrict__ wbig, unsigned short* __restrict__ w0b,
    float* __restrict__ biasbig, unsigned int* __restrict__ outenc,
    float* __restrict__ psumq, int* __restrict__ idx) {
  __shared__ float s[L_];
  if (blockIdx.x < 1280) {
    int gid = blockIdx.x * 256 + threadIdx.x;    // 327680 total
    if (gid < 65536) outenc[gid] = 0u;           // < encode of any real value
    if (gid < 1024) psumq[gid] = 0.0f;           // atomic BN-stat accumulators
    if (gid < 262144) {                          // wbig: 1024 rows x 256 f4-cols
      int e  = gid >> 8;
      int c4 = gid & 255;
      float4 v;
      if (c4 < 128) v = ((const float4*)(fc_w + e * D_))[c4];
      else          v = ((const float4*)(w1   + e * H_))[c4 - 128];
      ushort4v o = { f2bf(v.x), f2bf(v.y), f2bf(v.z), f2bf(v.w) };
      ((ushort4v*)wbig)[gid] = o;
      if (gid < E_) biasbig[gid] = fc_b[gid] + b1[gid];
    } else {                                     // w0b: 512x512
      int i2 = gid - 262144;                     // 65536
      float4 v = ((const float4*)w0)[i2];
      ushort4v o = { f2bf(v.x), f2bf(v.y), f2bf(v.z), f2bf(v.w) };
      ((ushort4v*)w0b)[i2] = o;
    }
  } else {
    // ---- stable top-k per batch via rank
    int b = blockIdx.x - 1280;                   // 0..63
    const float* row = atten + (size_t)b * L_ * L_;   // atten[b][0][:]
    for (int i = threadIdx.x; i < L_; i += 256) s[i] = (i == 0) ? -1.0f : row[i];
    __syncthreads();
    for (int i = threadIdx.x; i < L_; i += 256) {
      float si = s[i];
      int rank = 0;
      for (int j = 0; j < L_; ++j) {
        float sj = s[j];
        rank += (sj > si) || (sj == si && j < i);
      }
      if (rank < K_) idx[b * K_ + rank] = i;
    }
  }
}

// ---------------- kernel 2: gather + L2 normalize -> Abig[:,0:512] (bf16)
// wave-per-row: no LDS, no barriers; 4 rows per 256-thread block
__global__ __launch_bounds__(256) void gather_norm_kernel(
    const float* __restrict__ base, const int* __restrict__ idx,
    unsigned short* __restrict__ abig) {
  int r = blockIdx.x * 4 + (threadIdx.x >> 6);   // 0..N_-1
  int lane = threadIdx.x & 63;
  int b = r / K_;
  int tok = idx[r];
  const float* src = base + ((size_t)b * L_ + tok) * D_;
  float4 v0 = ((const float4*)src)[lane];        // 64 lanes * 8 = 512 floats
  float4 v1 = ((const float4*)src)[lane + 64];
  float ss = v0.x * v0.x + v0.y * v0.y + v0.z * v0.z + v0.w * v0.w
           + v1.x * v1.x + v1.y * v1.y + v1.z * v1.z + v1.w * v1.w;
  #pragma unroll
  for (int o = 1; o < 64; o <<= 1) ss += __shfl_xor(ss, o, 64);
  float inv = 1.0f / (sqrtf(ss) + 1e-8f);
  ushort4v o0 = { f2bf(v0.x * inv), f2bf(v0.y * inv), f2bf(v0.z * inv), f2bf(v0.w * inv) };
  ushort4v o1 = { f2bf(v1.x * inv), f2bf(v1.y * inv), f2bf(v1.z * inv), f2bf(v1.w * inv) };
  ushort4v* dst = (ushort4v*)(abig + (size_t)r * KBIG);
  dst[lane] = o0;
  dst[lane + 64] = o1;
}

// ---------------- bf16 MFMA GEMM, 128x128 tile, BK=64, 4 waves.
// LDS tile: 128 rows x 64 cols bf16, 8 slots of 8 cols per row (128B rows).
// XOR swizzle: slot s of row r holds global col-block s ^ (r&7).
// Staging (4 issues q per matrix): linear idx = q*256 + wave*64 + lane;
// row = q*32 + wave*8 + (lane>>3); LDS dst = base + 16*lane (m104 rule);
// lane fetches global col-block (lane&7) ^ ((lane>>3)&7) [== slot ^ (row&7)].
// Reader: frag for global k-block (4kk+quad) at slot (4kk+quad)^(l15&7);
// each lane-octet covers 8 distinct bank groups -> conflict-free.
// MODE 0 (GEMM1): write pre-BN h as bf16 + atomic BN stats into psum/psq[512].
// MODE 1 (GEMM2): no C write; fused per-batch column max via atomicMax(enc).
template <int MODE>
__global__ __launch_bounds__(256) void gemm_mfma_kernel(
    const unsigned short* __restrict__ A, int lda,
    const unsigned short* __restrict__ W, int ldw,
    const float* __restrict__ bias,
    unsigned short* __restrict__ Cbf, int ldc, int K,
    float* __restrict__ psum, float* __restrict__ psq,
    unsigned int* __restrict__ outenc) {
  __shared__ unsigned short As[128 * 64];
  __shared__ unsigned short Bs[128 * 64];
  const int tid  = threadIdx.x;
  const int wave = tid >> 6;
  const int lane = tid & 63;
  const int m0 = blockIdx.x * 128;
  const int n0 = blockIdx.y * 128;

  const int srow = wave * 8 + (lane >> 3);                 // + q*32
  const int g8   = ((lane & 7) ^ ((lane >> 3) & 7)) * 8;   // swizzled global col
  const int ldst = (wave * 64 + lane) * 8;                 // + q*2048 (ushorts)

  const int quad = lane >> 4;
  const int l15  = lane & 15;
  const int wm = (wave & 1) * 64;
  const int wn = (wave >> 1) * 64;
  const int slot0 = quad ^ (l15 & 7);          // kk adds XOR 4

  f32x4 acc[4][4];
  #pragma unroll
  for (int i = 0; i < 4; ++i)
    #pragma unroll
    for (int j = 0; j < 4; ++j)
      acc[i][j] = (f32x4)(0.0f);

  for (int k0 = 0; k0 < K; k0 += 64) {
    #pragma unroll
    for (int q = 0; q < 4; ++q) {
      GLOAD_LDS16(A + (size_t)(m0 + q * 32 + srow) * lda + k0 + g8,
                  &As[q * 2048 + ldst]);
      GLOAD_LDS16(W + (size_t)(n0 + q * 32 + srow) * ldw + k0 + g8,
                  &Bs[q * 2048 + ldst]);
    }
    __syncthreads();
    #pragma unroll
    for (int kk = 0; kk < 2; ++kk) {
      const int slot = slot0 ^ (kk * 4);
      bf16x8 af[4], bfr[4];
      #pragma unroll
      for (int i = 0; i < 4; ++i)
        af[i] = *(const bf16x8*)&As[(wm + 16 * i + l15) * 64 + slot * 8];
      #pragma unroll
      for (int j = 0; j < 4; ++j)
        bfr[j] = *(const bf16x8*)&Bs[(wn + 16 * j + l15) * 64 + slot * 8];
      #pragma unroll
      for (int i = 0; i < 4; ++i)
        #pragma unroll
        for (int j = 0; j < 4; ++j)
          acc[i][j] = __builtin_amdgcn_mfma_f32_16x16x32_bf16(af[i], bfr[j], acc[i][j], 0, 0, 0);
    }
    __syncthreads();
  }

  // epilogue: C/D layout col=lane&15, row=quad*4+reg
  if (MODE == 0) {
    // write pre-BN h (bf16) + per-column sum/sumsq via hardware f32 atomics.
    // waves {0,1} cover cols wn=0, {2,3} wn=64 -> 2 atomic adds per col per
    // block, 288 total per address over 144 m-tiles: low contention.
    #pragma unroll
    for (int j = 0; j < 4; ++j) {
      int col = n0 + wn + 16 * j + l15;
      float bb = bias[col];
      float sm = 0.f, sq = 0.f;
      #pragma unroll
      for (int i = 0; i < 4; ++i) {
        int row_base = m0 + wm + 16 * i + quad * 4;
        #pragma unroll
        for (int r = 0; r < 4; ++r) {
          float v = acc[i][j][r] + bb;
          Cbf[(size_t)(row_base + r) * ldc + col] = f2bf(v);
          sm += v; sq += v * v;
        }
      }
      sm += __shfl_xor(sm, 16, 64); sm += __shfl_xor(sm, 32, 64);
      sq += __shfl_xor(sq, 16, 64); sq += __shfl_xor(sq, 32, 64);
      if (quad == 0) {
        atomicAdd(&psum[col], sm);
        atomicAdd(&psq[col], sq);
      }
    }
  } else {
    // fused max over rows, grouped by batch (16-row bands are batch-uniform)
    #pragma unroll
    for (int j = 0; j < 4; ++j) {
      int col = n0 + wn + 16 * j + l15;
      float bb = bias[col];
      float m[4];
      #pragma unroll
      for (int i = 0; i < 4; ++i) {
        float v = fmaxf(fmaxf(acc[i][j][0], acc[i][j][1]),
                        fmaxf(acc[i][j][2], acc[i][j][3]));
        m[i] = v + bb;
      }
      #pragma unroll
      for (int i = 0; i < 4; ++i) {
        m[i] = fmaxf(m[i], __shfl_xor(m[i], 16, 64));
        m[i] = fmaxf(m[i], __shfl_xor(m[i], 32, 64));
      }
      if (quad == 0) {
        int base = m0 + wm;
        int cb = base / K_;
        float cur = m[0];
        #pragma unroll
        for (int i = 1; i < 4; ++i) {
          int bi = (base + 16 * i) / K_;
          if (bi == cb) cur = fmaxf(cur, m[i]);
          else { atomicMax(&outenc[cb * E_ + col], encf(cur)); cur = m[i]; cb = bi; }
        }
        atomicMax(&outenc[cb * E_ + col], encf(cur));
      }
    }
  }
}

// ---------------- BN stats finish: sc = rsig*gamma, sh = beta - mu*sc
__global__ __launch_bounds__(256) void bn_stats2_kernel(
    const float* __restrict__ psum, const float* __restrict__ psq,
    const float* __restrict__ gamma, const float* __restrict__ beta,
    float* __restrict__ scsh) {
  int c = blockIdx.x * 256 + threadIdx.x;       // grid 2 x 256 = 512 cols
  float S = psum[c], Q = psq[c];
  const float invN = 1.0f / (float)N_;
  float mu = S * invN;
  float var = Q * invN - mu * mu;
  float sc = rsqrtf(var + 1e-5f) * gamma[c];
  scsh[c] = sc;
  scsh[512 + c] = beta[c] - mu * sc;
}

// ---------------- BN apply + ReLU, bf16 in-place on Abig[:,512:1024]
__global__ __launch_bounds__(256) void bn_apply_kernel(
    unsigned short* __restrict__ abig, const float* __restrict__ scsh) {
  int gid = blockIdx.x * 256 + threadIdx.x;   // N_*64 threads, 8 elems each
  int r = gid >> 6;
  int c8 = gid & 63;
  int c = c8 * 8;
  ushort8v* p = (ushort8v*)(abig + (size_t)r * KBIG + H_) + c8;
  ushort8v v = *p;
  float4 sca = *(const float4*)&scsh[c];
  float4 scb = *(const float4*)&scsh[c + 4];
  float4 sha = *(const float4*)&scsh[512 + c];
  float4 shb = *(const float4*)&scsh[512 + c + 4];
  float sc[8] = {sca.x, sca.y, sca.z, sca.w, scb.x, scb.y, scb.z, scb.w};
  float sh[8] = {sha.x, sha.y, sha.z, sha.w, shb.x, shb.y, shb.z, shb.w};
  ushort8v o;
  #pragma unroll
  for (int j = 0; j < 8; ++j) {
    float x = bf2f(v[j]);
    o[j] = f2bf(fmaxf(x * sc[j] + sh[j], 0.0f));
  }
  *p = o;
}

// ---------------- decode encoded maxes -> d_out
__global__ __launch_bounds__(256) void decode_kernel(
    const unsigned int* __restrict__ outenc, float* __restrict__ out) {
  int gid = blockIdx.x * 256 + threadIdx.x;   // 65536
  out[gid] = decf(outenc[gid]);
}

extern "C" void kernel_launch(void* const* d_in, const int* in_sizes, int n_in,
                              void* d_out, int out_size, void* d_ws, size_t ws_size,
                              hipStream_t stream) {
  const float* base  = (const float*)d_in[0];   // [64,577,512]
  const float* atten = (const float*)d_in[1];   // [64,577,577]
  const float* fc_w  = (const float*)d_in[2];   // [1024,512]
  const float* fc_b  = (const float*)d_in[3];   // [1024]
  const float* w0    = (const float*)d_in[4];   // [512,512]
  const float* b0    = (const float*)d_in[5];   // [512]
  const float* gamma = (const float*)d_in[6];   // [512]
  const float* beta  = (const float*)d_in[7];   // [512]
  const float* w1    = (const float*)d_in[8];   // [1024,512]
  const float* b1    = (const float*)d_in[9];   // [1024]
  float* out = (float*)d_out;

  char* ws = (char*)d_ws;
  unsigned short* wbig    = (unsigned short*)(ws + OFF_WBIG);
  unsigned short* w0b     = (unsigned short*)(ws + OFF_W0B);
  float*          biasbig = (float*)(ws + OFF_BIASBIG);
  float*          scsh    = (float*)(ws + OFF_SCSH);
  int*            idx     = (int*)  (ws + OFF_IDX);
  float*          psum    = (float*)(ws + OFF_PSUM);
  float*          psq     = psum + 512;
  unsigned int*   outenc  = (unsigned int*)(ws + OFF_OUTENC);
  unsigned short* abig    = (unsigned short*)(ws + OFF_ABIG);

  // 1. pack fused weight/bias (bf16) + zero outenc/psum/psq + top-k (fused)
  prep_topk_kernel<<<1344, 256, 0, stream>>>(fc_w, fc_b, w0, w1, b1, atten,
                                             wbig, w0b, biasbig, outenc,
                                             psum, idx);
  // 2. gather + l2norm -> Abig[:,0:512] bf16 (wave-per-row)
  gather_norm_kernel<<<N_ / 4, 256, 0, stream>>>(base, idx, abig);
  // 3. GEMM1: pre-BN h (bf16) -> Abig[:,512:1024] + atomic BN stats
  {
    dim3 grid(MTILES, H_ / 128);
    gemm_mfma_kernel<0><<<grid, 256, 0, stream>>>(abig, KBIG, w0b, D_, b0,
                                                  abig + H_, KBIG, D_,
                                                  psum, psq, nullptr);
  }
  // 4. BN stats finish -> sc/sh
  bn_stats2_kernel<<<2, 256, 0, stream>>>(psum, psq, gamma, beta, scsh);
  // 5. BN apply + ReLU in place (bf16)
  bn_apply_kernel<<<(N_ * 64) / 256, 256, 0, stream>>>(abig, scsh);
  // 6. fused GEMM2 + per-batch column max (no local materialization)
  {
    dim3 grid(MTILES, E_ / 128);
    gemm_mfma_kernel<1><<<grid, 256, 0, stream>>>(abig, KBIG, wbig, KBIG, biasbig,
                                                  nullptr, 0, KBIG, nullptr, nullptr,
                                                  outenc);
  }
  // 7. decode -> out
  decode_kernel<<<(B_ * E_) / 256, 256, 0, stream>>>(outenc, out);
}

// Round 3
// 294.533 us; speedup vs baseline: 1.0108x; 1.0108x over previous
//
#include <hip/hip_runtime.h>
#include <math.h>

// Problem constants
#define B_   64
#define L_   577
#define D_   512
#define E_   1024
#define H_   512
#define K_   288            // selected tokens per batch
#define N_   (B_ * K_)      // 18432 total rows
#define KBIG 1024           // concatenated K for fused GEMM2
#define MTILES (N_ / 128)   // 144 = 8 XCDs * 18

typedef __attribute__((ext_vector_type(8))) __bf16 bf16x8;
typedef __attribute__((ext_vector_type(4))) float f32x4;
typedef __attribute__((ext_vector_type(4))) unsigned short ushort4v;
typedef __attribute__((ext_vector_type(8))) unsigned short ushort8v;

// ---------------- workspace layout (bytes) ----------------
#define OFF_WBIG    0                    // 1024*1024 bf16 = 2,097,152
#define OFF_W0B     2097152              // 512*512 bf16   =   524,288
#define OFF_BIASBIG 2621440              // 1024 f32
#define OFF_SCSH    2625536              // 1024 f32 (sc=rsig*gamma, sh=beta-mu*sc)
#define OFF_IDX     2629632              // 18432 i32 = 73,728
#define OFF_PSUM    2703360              // 512 f32 sum + 512 f32 sumsq (atomic)
#define OFF_OUTENC  3293184              // 64*1024 u32 = 262,144
#define OFF_ABIG    3555328              // N*1024 bf16 = 37,748,736

static __device__ __forceinline__ unsigned short f2bf(float f) {
  unsigned int u = __builtin_bit_cast(unsigned int, f);
  u = (u + 0x7fffu + ((u >> 16) & 1u)) >> 16;
  return (unsigned short)u;
}
static __device__ __forceinline__ float bf2f(unsigned short s) {
  unsigned int u = ((unsigned int)s) << 16;
  return __builtin_bit_cast(float, u);
}

// monotone fp32 <-> uint encoding for atomicMax on floats
static __device__ __forceinline__ unsigned int encf(float f) {
  unsigned int u = __builtin_bit_cast(unsigned int, f);
  return (u & 0x80000000u) ? ~u : (u | 0x80000000u);
}
static __device__ __forceinline__ float decf(unsigned int e) {
  unsigned int u = (e & 0x80000000u) ? (e ^ 0x80000000u) : ~e;
  return __builtin_bit_cast(float, u);
}

#define GLOAD_LDS16(g, l)                                          \
  __builtin_amdgcn_global_load_lds(                                \
      (const __attribute__((address_space(1))) void*)(g),          \
      (__attribute__((address_space(3))) void*)(l), 16, 0, 0)

// ---------------- kernel 1: pack Wbig(bf16)=[fc_w|mlp_w1], biasbig=fc_b+b1,
//                  W0(bf16), zero outenc + psum/psq, AND top-k (fused)
__global__ __launch_bounds__(256) void prep_topk_kernel(
    const float* __restrict__ fc_w, const float* __restrict__ fc_b,
    const float* __restrict__ w0,   const float* __restrict__ w1,
    const float* __restrict__ b1,   const float* __restrict__ atten,
    unsigned short* __restrict__ wbig, unsigned short* __restrict__ w0b,
    float* __restrict__ biasbig, unsigned int* __restrict__ outenc,
    float* __restrict__ psumq, int* __restrict__ idx) {
  __shared__ float s[L_];
  if (blockIdx.x < 1280) {
    int gid = blockIdx.x * 256 + threadIdx.x;    // 327680 total
    if (gid < 65536) outenc[gid] = 0u;           // < encode of any real value
    if (gid < 1024) psumq[gid] = 0.0f;           // atomic BN-stat accumulators
    if (gid < 262144) {                          // wbig: 1024 rows x 256 f4-cols
      int e  = gid >> 8;
      int c4 = gid & 255;
      float4 v;
      if (c4 < 128) v = ((const float4*)(fc_w + e * D_))[c4];
      else          v = ((const float4*)(w1   + e * H_))[c4 - 128];
      ushort4v o = { f2bf(v.x), f2bf(v.y), f2bf(v.z), f2bf(v.w) };
      ((ushort4v*)wbig)[gid] = o;
      if (gid < E_) biasbig[gid] = fc_b[gid] + b1[gid];
    } else {                                     // w0b: 512x512
      int i2 = gid - 262144;                     // 65536
      float4 v = ((const float4*)w0)[i2];
      ushort4v o = { f2bf(v.x), f2bf(v.y), f2bf(v.z), f2bf(v.w) };
      ((ushort4v*)w0b)[i2] = o;
    }
  } else {
    // ---- stable top-k per batch via rank
    int b = blockIdx.x - 1280;                   // 0..63
    const float* row = atten + (size_t)b * L_ * L_;   // atten[b][0][:]
    for (int i = threadIdx.x; i < L_; i += 256) s[i] = (i == 0) ? -1.0f : row[i];
    __syncthreads();
    for (int i = threadIdx.x; i < L_; i += 256) {
      float si = s[i];
      int rank = 0;
      for (int j = 0; j < L_; ++j) {
        float sj = s[j];
        rank += (sj > si) || (sj == si && j < i);
      }
      if (rank < K_) idx[b * K_ + rank] = i;
    }
  }
}

// ---------------- kernel 2: gather + L2 normalize -> Abig[:,0:512] (bf16)
// wave-per-row: no LDS, no barriers; 4 rows per 256-thread block
__global__ __launch_bounds__(256) void gather_norm_kernel(
    const float* __restrict__ base, const int* __restrict__ idx,
    unsigned short* __restrict__ abig) {
  int r = blockIdx.x * 4 + (threadIdx.x >> 6);   // 0..N_-1
  int lane = threadIdx.x & 63;
  int b = r / K_;
  int tok = idx[r];
  const float* src = base + ((size_t)b * L_ + tok) * D_;
  float4 v0 = ((const float4*)src)[lane];        // 64 lanes * 8 = 512 floats
  float4 v1 = ((const float4*)src)[lane + 64];
  float ss = v0.x * v0.x + v0.y * v0.y + v0.z * v0.z + v0.w * v0.w
           + v1.x * v1.x + v1.y * v1.y + v1.z * v1.z + v1.w * v1.w;
  #pragma unroll
  for (int o = 1; o < 64; o <<= 1) ss += __shfl_xor(ss, o, 64);
  float inv = 1.0f / (sqrtf(ss) + 1e-8f);
  ushort4v o0 = { f2bf(v0.x * inv), f2bf(v0.y * inv), f2bf(v0.z * inv), f2bf(v0.w * inv) };
  ushort4v o1 = { f2bf(v1.x * inv), f2bf(v1.y * inv), f2bf(v1.z * inv), f2bf(v1.w * inv) };
  ushort4v* dst = (ushort4v*)(abig + (size_t)r * KBIG);
  dst[lane] = o0;
  dst[lane + 64] = o1;
}

// ---------------- bf16 MFMA GEMM, 128x128 tile, BK=64, 4 waves.
// LDS tile: 128 rows x 64 cols bf16, 8 slots of 8 cols per row (128B rows).
// XOR swizzle: slot s of row r holds global col-block s ^ (r&7).
// Staging (4 issues q per matrix): linear idx = q*256 + wave*64 + lane;
// row = q*32 + wave*8 + (lane>>3); LDS dst = base + 16*lane (m104 rule);
// lane fetches global col-block (lane&7) ^ ((lane>>3)&7) [== slot ^ (row&7)].
// Reader: frag for global k-block (4kk+quad) at slot (4kk+quad)^(l15&7);
// each lane-octet covers 8 distinct bank groups -> conflict-free.
//
// XCD-aware block swizzle (T1): 1-D grid, bijective. Block b -> XCD b&7
// (dispatch round-robins XCDs). XCD x owns m-tiles [18x, 18x+18), iterating
// n FASTEST within each m-tile. Effect: the A m-panel (256 KB) stays hot in
// the XCD's private L2 across its NT consecutive n-blocks, and the whole W
// (<=2 MB) becomes L2-resident per XCD -> ~NTx less Infinity-Cache traffic.
// MODE 0 (GEMM1): NT=4; write pre-BN h as bf16 + atomic BN stats.
// MODE 1 (GEMM2): NT=8; no C write; per-batch column max via atomicMax(enc).
template <int MODE>
__global__ __launch_bounds__(256) void gemm_mfma_kernel(
    const unsigned short* __restrict__ A, int lda,
    const unsigned short* __restrict__ W, int ldw,
    const float* __restrict__ bias,
    unsigned short* __restrict__ Cbf, int ldc, int K,
    float* __restrict__ psum, float* __restrict__ psq,
    unsigned int* __restrict__ outenc) {
  __shared__ unsigned short As[128 * 64];
  __shared__ unsigned short Bs[128 * 64];
  const int tid  = threadIdx.x;
  const int wave = tid >> 6;
  const int lane = tid & 63;

  // XCD-chunked, n-fastest block mapping (bijective: grid = 8*18*NT)
  const int bx  = blockIdx.x;
  const int xcd = bx & 7;
  const int sq_ = bx >> 3;
  int mt, nt;
  if (MODE == 0) { mt = xcd * 18 + (sq_ >> 2); nt = sq_ & 3; }   // grid 576
  else           { mt = xcd * 18 + (sq_ >> 3); nt = sq_ & 7; }   // grid 1152
  const int m0 = mt * 128;
  const int n0 = nt * 128;

  const int srow = wave * 8 + (lane >> 3);                 // + q*32
  const int g8   = ((lane & 7) ^ ((lane >> 3) & 7)) * 8;   // swizzled global col
  const int ldst = (wave * 64 + lane) * 8;                 // + q*2048 (ushorts)

  const int quad = lane >> 4;
  const int l15  = lane & 15;
  const int wm = (wave & 1) * 64;
  const int wn = (wave >> 1) * 64;
  const int slot0 = quad ^ (l15 & 7);          // kk adds XOR 4

  f32x4 acc[4][4];
  #pragma unroll
  for (int i = 0; i < 4; ++i)
    #pragma unroll
    for (int j = 0; j < 4; ++j)
      acc[i][j] = (f32x4)(0.0f);

  for (int k0 = 0; k0 < K; k0 += 64) {
    #pragma unroll
    for (int q = 0; q < 4; ++q) {
      GLOAD_LDS16(A + (size_t)(m0 + q * 32 + srow) * lda + k0 + g8,
                  &As[q * 2048 + ldst]);
      GLOAD_LDS16(W + (size_t)(n0 + q * 32 + srow) * ldw + k0 + g8,
                  &Bs[q * 2048 + ldst]);
    }
    __syncthreads();
    #pragma unroll
    for (int kk = 0; kk < 2; ++kk) {
      const int slot = slot0 ^ (kk * 4);
      bf16x8 af[4], bfr[4];
      #pragma unroll
      for (int i = 0; i < 4; ++i)
        af[i] = *(const bf16x8*)&As[(wm + 16 * i + l15) * 64 + slot * 8];
      #pragma unroll
      for (int j = 0; j < 4; ++j)
        bfr[j] = *(const bf16x8*)&Bs[(wn + 16 * j + l15) * 64 + slot * 8];
      #pragma unroll
      for (int i = 0; i < 4; ++i)
        #pragma unroll
        for (int j = 0; j < 4; ++j)
          acc[i][j] = __builtin_amdgcn_mfma_f32_16x16x32_bf16(af[i], bfr[j], acc[i][j], 0, 0, 0);
    }
    __syncthreads();
  }

  // epilogue: C/D layout col=lane&15, row=quad*4+reg
  if (MODE == 0) {
    // write pre-BN h (bf16) + per-column sum/sumsq via hardware f32 atomics.
    #pragma unroll
    for (int j = 0; j < 4; ++j) {
      int col = n0 + wn + 16 * j + l15;
      float bb = bias[col];
      float sm = 0.f, sq = 0.f;
      #pragma unroll
      for (int i = 0; i < 4; ++i) {
        int row_base = m0 + wm + 16 * i + quad * 4;
        #pragma unroll
        for (int r = 0; r < 4; ++r) {
          float v = acc[i][j][r] + bb;
          Cbf[(size_t)(row_base + r) * ldc + col] = f2bf(v);
          sm += v; sq += v * v;
        }
      }
      sm += __shfl_xor(sm, 16, 64); sm += __shfl_xor(sm, 32, 64);
      sq += __shfl_xor(sq, 16, 64); sq += __shfl_xor(sq, 32, 64);
      if (quad == 0) {
        atomicAdd(&psum[col], sm);
        atomicAdd(&psq[col], sq);
      }
    }
  } else {
    // fused max over rows, grouped by batch (16-row bands are batch-uniform)
    #pragma unroll
    for (int j = 0; j < 4; ++j) {
      int col = n0 + wn + 16 * j + l15;
      float bb = bias[col];
      float m[4];
      #pragma unroll
      for (int i = 0; i < 4; ++i) {
        float v = fmaxf(fmaxf(acc[i][j][0], acc[i][j][1]),
                        fmaxf(acc[i][j][2], acc[i][j][3]));
        m[i] = v + bb;
      }
      #pragma unroll
      for (int i = 0; i < 4; ++i) {
        m[i] = fmaxf(m[i], __shfl_xor(m[i], 16, 64));
        m[i] = fmaxf(m[i], __shfl_xor(m[i], 32, 64));
      }
      if (quad == 0) {
        int base = m0 + wm;
        int cb = base / K_;
        float cur = m[0];
        #pragma unroll
        for (int i = 1; i < 4; ++i) {
          int bi = (base + 16 * i) / K_;
          if (bi == cb) cur = fmaxf(cur, m[i]);
          else { atomicMax(&outenc[cb * E_ + col], encf(cur)); cur = m[i]; cb = bi; }
        }
        atomicMax(&outenc[cb * E_ + col], encf(cur));
      }
    }
  }
}

// ---------------- BN stats finish: sc = rsig*gamma, sh = beta - mu*sc
__global__ __launch_bounds__(256) void bn_stats2_kernel(
    const float* __restrict__ psum, const float* __restrict__ psq,
    const float* __restrict__ gamma, const float* __restrict__ beta,
    float* __restrict__ scsh) {
  int c = blockIdx.x * 256 + threadIdx.x;       // grid 2 x 256 = 512 cols
  float S = psum[c], Q = psq[c];
  const float invN = 1.0f / (float)N_;
  float mu = S * invN;
  float var = Q * invN - mu * mu;
  float sc = rsqrtf(var + 1e-5f) * gamma[c];
  scsh[c] = sc;
  scsh[512 + c] = beta[c] - mu * sc;
}

// ---------------- BN apply + ReLU, bf16 in-place on Abig[:,512:1024]
__global__ __launch_bounds__(256) void bn_apply_kernel(
    unsigned short* __restrict__ abig, const float* __restrict__ scsh) {
  int gid = blockIdx.x * 256 + threadIdx.x;   // N_*64 threads, 8 elems each
  int r = gid >> 6;
  int c8 = gid & 63;
  int c = c8 * 8;
  ushort8v* p = (ushort8v*)(abig + (size_t)r * KBIG + H_) + c8;
  ushort8v v = *p;
  float4 sca = *(const float4*)&scsh[c];
  float4 scb = *(const float4*)&scsh[c + 4];
  float4 sha = *(const float4*)&scsh[512 + c];
  float4 shb = *(const float4*)&scsh[512 + c + 4];
  float sc[8] = {sca.x, sca.y, sca.z, sca.w, scb.x, scb.y, scb.z, scb.w};
  float sh[8] = {sha.x, sha.y, sha.z, sha.w, shb.x, shb.y, shb.z, shb.w};
  ushort8v o;
  #pragma unroll
  for (int j = 0; j < 8; ++j) {
    float x = bf2f(v[j]);
    o[j] = f2bf(fmaxf(x * sc[j] + sh[j], 0.0f));
  }
  *p = o;
}

// ---------------- decode encoded maxes -> d_out
__global__ __launch_bounds__(256) void decode_kernel(
    const unsigned int* __restrict__ outenc, float* __restrict__ out) {
  int gid = blockIdx.x * 256 + threadIdx.x;   // 65536
  out[gid] = decf(outenc[gid]);
}

extern "C" void kernel_launch(void* const* d_in, const int* in_sizes, int n_in,
                              void* d_out, int out_size, void* d_ws, size_t ws_size,
                              hipStream_t stream) {
  const float* base  = (const float*)d_in[0];   // [64,577,512]
  const float* atten = (const float*)d_in[1];   // [64,577,577]
  const float* fc_w  = (const float*)d_in[2];   // [1024,512]
  const float* fc_b  = (const float*)d_in[3];   // [1024]
  const float* w0    = (const float*)d_in[4];   // [512,512]
  const float* b0    = (const float*)d_in[5];   // [512]
  const float* gamma = (const float*)d_in[6];   // [512]
  const float* beta  = (const float*)d_in[7];   // [512]
  const float* w1    = (const float*)d_in[8];   // [1024,512]
  const float* b1    = (const float*)d_in[9];   // [1024]
  float* out = (float*)d_out;

  char* ws = (char*)d_ws;
  unsigned short* wbig    = (unsigned short*)(ws + OFF_WBIG);
  unsigned short* w0b     = (unsigned short*)(ws + OFF_W0B);
  float*          biasbig = (float*)(ws + OFF_BIASBIG);
  float*          scsh    = (float*)(ws + OFF_SCSH);
  int*            idx     = (int*)  (ws + OFF_IDX);
  float*          psum    = (float*)(ws + OFF_PSUM);
  float*          psq     = psum + 512;
  unsigned int*   outenc  = (unsigned int*)(ws + OFF_OUTENC);
  unsigned short* abig    = (unsigned short*)(ws + OFF_ABIG);

  // 1. pack fused weight/bias (bf16) + zero outenc/psum/psq + top-k (fused)
  prep_topk_kernel<<<1344, 256, 0, stream>>>(fc_w, fc_b, w0, w1, b1, atten,
                                             wbig, w0b, biasbig, outenc,
                                             psum, idx);
  // 2. gather + l2norm -> Abig[:,0:512] bf16 (wave-per-row)
  gather_norm_kernel<<<N_ / 4, 256, 0, stream>>>(base, idx, abig);
  // 3. GEMM1: pre-BN h (bf16) -> Abig[:,512:1024] + atomic BN stats
  //    1-D grid, XCD-swizzled (8 xcd * 18 mtile * 4 ntile = 576)
  gemm_mfma_kernel<0><<<576, 256, 0, stream>>>(abig, KBIG, w0b, D_, b0,
                                               abig + H_, KBIG, D_,
                                               psum, psq, nullptr);
  // 4. BN stats finish -> sc/sh
  bn_stats2_kernel<<<2, 256, 0, stream>>>(psum, psq, gamma, beta, scsh);
  // 5. BN apply + ReLU in place (bf16)
  bn_apply_kernel<<<(N_ * 64) / 256, 256, 0, stream>>>(abig, scsh);
  // 6. fused GEMM2 + per-batch column max, XCD-swizzled (8*18*8 = 1152)
  gemm_mfma_kernel<1><<<1152, 256, 0, stream>>>(abig, KBIG, wbig, KBIG, biasbig,
                                                nullptr, 0, KBIG, nullptr, nullptr,
                                                outenc);
  // 7. decode -> out
  decode_kernel<<<(B_ * E_) / 256, 256, 0, stream>>>(outenc, out);
}